// Round 17
// baseline (136.507 us; speedup 1.0000x reference)
//
#include <hip/hip_runtime.h>

#define NROWS 65536
#define KDIM  512
constexpr float BN_EPS = 1e-5f;

using short8 = __attribute__((ext_vector_type(8))) short;
using f32x4  = __attribute__((ext_vector_type(4))) float;

#define BM 128

// async global->LDS, 16B per lane
__device__ __forceinline__ void gload_lds16(const void* g, void* l) {
  __builtin_amdgcn_global_load_lds(
      (const __attribute__((address_space(1))) void*)g,
      (__attribute__((address_space(3))) void*)l, 16, 0, 0);
}

// RNE fp32 -> bf16 pack of 8 floats
__device__ __forceinline__ short8 cvthi8(const float4& a, const float4& b) {
  const float e[8] = {a.x, a.y, a.z, a.w, b.x, b.y, b.z, b.w};
  short8 h;
  #pragma unroll
  for (int i = 0; i < 8; ++i) {
    unsigned u = __float_as_uint(e[i]);
    u += 0x7FFFu + ((u >> 16) & 1u);
    h[i] = (short)(u >> 16);
  }
  return h;
}

// ---------------- prep: C1 -> fragment-tiled bf16 (RNE) ----------------
// entry e = kg*512 + col holds C1[kg*8 + i][col], i=0..7 (one B-fragment).
__global__ __launch_bounds__(256)
void prep_c1(const float* __restrict__ C1, short8* __restrict__ c1tH) {
  const int e   = blockIdx.x * 256 + threadIdx.x;   // 0..32767
  const int col = e & 511;
  const int kg  = e >> 9;
  short8 hi;
  #pragma unroll
  for (int i = 0; i < 8; ++i) {
    const float x = C1[(size_t)(kg * 8 + i) * KDIM + col];   // coalesced
    unsigned u = __float_as_uint(x);
    u += 0x7FFFu + ((u >> 16) & 1u);
    hi[i] = (short)(u >> 16);
  }
  c1tH[e] = hi;
}

// ---------------- quad: 3-buffer counted-vmcnt pipeline (T4) ----------------
// quad[n] = x_n^T C1 x_n (1-pass bf16 MFMA), fused column stats.
// 16 waves = 4 row-groups x 4 col-groups (wave tile 32 rows x 128 cols).
// Per phase kt: issue stage(kt+2) via global_load_lds (B bf16 32KB + A raw
// fp32 16KB, source-preswizzled); compute kt from LDS (ds_read + in-reg
// cvt of A + 16 MFMA); then `s_waitcnt vmcnt(3)` (completes stage(kt+1),
// 1.5 phases old => ~zero drain; stage(kt+2) stays in flight) + s_barrier.
// Every wave waits its OWN stage(kt+1) before the barrier, so the barrier
// makes completion global — no cross-wave vmcnt race. This replaces the
// drain-0 __syncthreads (r16's ~85% stall; T4 mechanism, m218).
__global__ __launch_bounds__(1024)
void quad_kernel(const float* __restrict__ X, const short8* __restrict__ c1tH,
                 float* __restrict__ quad,
                 float* __restrict__ colS1, float* __restrict__ colS2,
                 float* __restrict__ colS3, double* __restrict__ qsums) {
  __shared__ short8 Bs[3][2048];      // 3 x 32 KB  (bf16 fragment-tiled)
  __shared__ float  As[3][4096];      // 3 x 16 KB  (fp32 [128][32], chunk-swizzled)
  __shared__ float qPart[4][BM];
  __shared__ float qLds[BM];

  const int tid  = threadIdx.x;
  const int lane = tid & 63;
  const int w    = tid >> 6;          // wave 0..15
  const int wr   = w >> 2;            // row-group (0..3): rows wr*32..+31
  const int wc   = w & 3;             // col-group (0..3): cols wc*128..+127
  const int g    = lane >> 4;         // k-group 0..3
  const int lr   = lane & 15;
  const int r0   = blockIdx.x * BM;

  // A staging: thread t stages 16B chunk (t&7) of row (t>>3), SOURCE
  // pre-swizzled (chunk c read from source chunk c^(row&7)) so the
  // compute-side reads at [row*32 + (chunk^(row&7))*4] are conflict-free.
  const int arow = tid >> 3;
  const int ac   = tid & 7;
  const float* asrc = X + (size_t)(r0 + arow) * KDIM + ((ac ^ (arow & 7)) * 4);

#define STAGE(bufi, kt)                                                    \
  {                                                                        \
    gload_lds16(c1tH + (kt) * 2048 + tid,        &Bs[bufi][tid]);          \
    gload_lds16(c1tH + (kt) * 2048 + 1024 + tid, &Bs[bufi][1024 + tid]);   \
    gload_lds16(asrc + (kt) * 32,                &As[bufi][tid * 4]);      \
  }

  f32x4 acc[2][8];
  #pragma unroll
  for (int rf = 0; rf < 2; ++rf)
    #pragma unroll
    for (int cf = 0; cf < 8; ++cf)
      acc[rf][cf] = (f32x4){0.f, 0.f, 0.f, 0.f};

  // ---- prologue: stage kt=0 and kt=1; wait only kt=0 (vmcnt(3)) ----
  STAGE(0, 0);
  STAGE(1, 1);
  asm volatile("s_waitcnt vmcnt(3)" ::: "memory");
  __builtin_amdgcn_s_barrier();
  __builtin_amdgcn_sched_barrier(0);

  #pragma unroll
  for (int kt = 0; kt < 16; ++kt) {
    const int buf = kt % 3;
    // ---- issue stage(kt+2) (lands ~2 phases from now) ----
    if (kt < 14) STAGE((kt + 2) % 3, kt + 2);
    // ---- compute kt from LDS ----
    short8 A0, A1;
    {
      const int row0 = wr * 32 + lr;
      const float4 a00 = *(const float4*)&As[buf][row0 * 32 + (((2 * g) ^ (row0 & 7)) * 4)];
      const float4 a01 = *(const float4*)&As[buf][row0 * 32 + (((2 * g + 1) ^ (row0 & 7)) * 4)];
      A0 = cvthi8(a00, a01);
      const int row1 = row0 + 16;
      const float4 a10 = *(const float4*)&As[buf][row1 * 32 + (((2 * g) ^ (row1 & 7)) * 4)];
      const float4 a11 = *(const float4*)&As[buf][row1 * 32 + (((2 * g + 1) ^ (row1 & 7)) * 4)];
      A1 = cvthi8(a10, a11);
    }
    const int fb = g * 512 + wc * 128 + lr;
    {
      const short8 b0 = Bs[buf][fb];
      const short8 b1 = Bs[buf][fb + 16];
      const short8 b2 = Bs[buf][fb + 32];
      const short8 b3 = Bs[buf][fb + 48];
      acc[0][0] = __builtin_amdgcn_mfma_f32_16x16x32_bf16(A0, b0, acc[0][0], 0, 0, 0);
      acc[1][0] = __builtin_amdgcn_mfma_f32_16x16x32_bf16(A1, b0, acc[1][0], 0, 0, 0);
      acc[0][1] = __builtin_amdgcn_mfma_f32_16x16x32_bf16(A0, b1, acc[0][1], 0, 0, 0);
      acc[1][1] = __builtin_amdgcn_mfma_f32_16x16x32_bf16(A1, b1, acc[1][1], 0, 0, 0);
      acc[0][2] = __builtin_amdgcn_mfma_f32_16x16x32_bf16(A0, b2, acc[0][2], 0, 0, 0);
      acc[1][2] = __builtin_amdgcn_mfma_f32_16x16x32_bf16(A1, b2, acc[1][2], 0, 0, 0);
      acc[0][3] = __builtin_amdgcn_mfma_f32_16x16x32_bf16(A0, b3, acc[0][3], 0, 0, 0);
      acc[1][3] = __builtin_amdgcn_mfma_f32_16x16x32_bf16(A1, b3, acc[1][3], 0, 0, 0);
    }
    {
      const short8 b4 = Bs[buf][fb + 64];
      const short8 b5 = Bs[buf][fb + 80];
      const short8 b6 = Bs[buf][fb + 96];
      const short8 b7 = Bs[buf][fb + 112];
      acc[0][4] = __builtin_amdgcn_mfma_f32_16x16x32_bf16(A0, b4, acc[0][4], 0, 0, 0);
      acc[1][4] = __builtin_amdgcn_mfma_f32_16x16x32_bf16(A1, b4, acc[1][4], 0, 0, 0);
      acc[0][5] = __builtin_amdgcn_mfma_f32_16x16x32_bf16(A0, b5, acc[0][5], 0, 0, 0);
      acc[1][5] = __builtin_amdgcn_mfma_f32_16x16x32_bf16(A1, b5, acc[1][5], 0, 0, 0);
      acc[0][6] = __builtin_amdgcn_mfma_f32_16x16x32_bf16(A0, b6, acc[0][6], 0, 0, 0);
      acc[1][6] = __builtin_amdgcn_mfma_f32_16x16x32_bf16(A1, b6, acc[1][6], 0, 0, 0);
      acc[0][7] = __builtin_amdgcn_mfma_f32_16x16x32_bf16(A0, b7, acc[0][7], 0, 0, 0);
      acc[1][7] = __builtin_amdgcn_mfma_f32_16x16x32_bf16(A1, b7, acc[1][7], 0, 0, 0);
    }
    // ---- counted pre-barrier wait: stage(kt+1) done, stage(kt+2) in flight ----
    if (kt < 14) {
      asm volatile("s_waitcnt vmcnt(3)" ::: "memory");
    } else if (kt == 14) {
      asm volatile("s_waitcnt vmcnt(0)" ::: "memory");
    }
    if (kt < 15) {
      __builtin_amdgcn_s_barrier();
      __builtin_amdgcn_sched_barrier(0);
    }
  }
#undef STAGE

  // ---- epilogue: row-dot against X for this wave's 128-col slice ----
  #pragma unroll
  for (int rf = 0; rf < 2; ++rf)
    #pragma unroll
    for (int p = 0; p < 4; ++p) {
      const int row = wr * 32 + rf * 16 + g * 4 + p;
      const float* xr = X + (size_t)(r0 + row) * KDIM + wc * 128;
      float s = 0.f;
      #pragma unroll
      for (int cf = 0; cf < 8; ++cf)
        s += acc[rf][cf][p] * xr[cf * 16 + lr];
      s += __shfl_xor(s, 1, 64);
      s += __shfl_xor(s, 2, 64);
      s += __shfl_xor(s, 4, 64);
      s += __shfl_xor(s, 8, 64);
      if (lr == 0) qPart[wc][row] = s;
    }
  __syncthreads();
  if (tid < BM) {
    const float q = qPart[0][tid] + qPart[1][tid] + qPart[2][tid] + qPart[3][tid];
    quad[r0 + tid] = q;
    qLds[tid] = q;
  }
  __syncthreads();
  // ---- fused column stats: 1024 threads = 512 cols x 2 row-halves ----
  {
    const int col   = tid & 511;
    const int rbase = (tid >> 9) * 64;
    float s1 = 0.f, s2 = 0.f, s3 = 0.f;
    for (int r = rbase; r < rbase + 64; ++r) {
      const float q = qLds[r];
      const float x = X[(size_t)(r0 + r) * KDIM + col];
      s1 += x; s2 += x * x; s3 += q * x;
    }
    atomicAdd(&colS1[col], s1);
    atomicAdd(&colS2[col], s2);
    atomicAdd(&colS3[col], s3);
  }
  if (tid < BM) {   // two waves: each reduces 64 lanes of q, q^2
    double q = (double)qLds[tid];
    double q2 = q * q;
    #pragma unroll
    for (int m = 1; m < 64; m <<= 1) {
      q  += __shfl_xor(q,  m, 64);
      q2 += __shfl_xor(q2, m, 64);
    }
    if ((tid & 63) == 0) { atomicAdd(&qsums[0], q); atomicAdd(&qsums[1], q2); }
  }
}

// ---------------- finalize per-feature mean / inv_std ----------------
__global__ void finalize_kernel(const float* __restrict__ colS1, const float* __restrict__ colS2,
                                const float* __restrict__ colS3, const double* __restrict__ qsums,
                                const float* __restrict__ C2, const float* __restrict__ C3,
                                float* __restrict__ mean, float* __restrict__ inv_std) {
  const int k = blockIdx.x * blockDim.x + threadIdx.x;
  if (k >= KDIM) return;
  const double invN = 1.0 / (double)NROWS;
  const double meanQ = qsums[0] * invN;
  const double varQ  = qsums[1] * invN - meanQ * meanQ;
  const float meanX = colS1[k] * (float)invN;
  const float varX  = colS2[k] * (float)invN - meanX * meanX;
  const float covQX = colS3[k] * (float)invN - (float)meanQ * meanX;
  const float c2 = C2[k];
  const float c3 = C3[0];
  const float m = (float)meanQ + c2 * meanX + c3;
  const float v = (float)varQ + c2 * c2 * varX + 2.0f * c2 * covQX;
  mean[k] = m;
  inv_std[k] = 1.0f / sqrtf(v + BN_EPS);
}

// ---------------- normalize + write ----------------
__global__ __launch_bounds__(256)
void normalize_kernel(const float* __restrict__ X, const float* __restrict__ quad,
                      const float* __restrict__ C2, const float* __restrict__ C3,
                      const float* __restrict__ mean, const float* __restrict__ inv_std,
                      float* __restrict__ out) {
  const int idx = blockIdx.x * blockDim.x + threadIdx.x;  // float4 index
  const int n = idx >> 7;
  const int j4 = idx & 127;
  const float q = quad[n];
  const float c3 = C3[0];
  const float4 x  = *(const float4*)&X[(size_t)idx * 4];
  const float4 c2 = *(const float4*)&C2[j4 * 4];
  const float4 m  = *(const float4*)&mean[j4 * 4];
  const float4 iv = *(const float4*)&inv_std[j4 * 4];
  float4 o;
  o.x = (q + c2.x * x.x + c3 - m.x) * iv.x;
  o.y = (q + c2.y * x.y + c3 - m.y) * iv.y;
  o.z = (q + c2.z * x.z + c3 - m.z) * iv.z;
  o.w = (q + c2.w * x.w + c3 - m.w) * iv.w;
  *(float4*)&out[(size_t)idx * 4] = o;
}

extern "C" void kernel_launch(void* const* d_in, const int* in_sizes, int n_in,
                              void* d_out, int out_size, void* d_ws, size_t ws_size,
                              hipStream_t stream) {
  const float* X  = (const float*)d_in[0];
  const float* C1 = (const float*)d_in[1];
  const float* C2 = (const float*)d_in[2];
  const float* C3 = (const float*)d_in[3];
  float* out = (float*)d_out;

  char* ws = (char*)d_ws;
  float*  quad    = (float*)ws;                                        // 256 KB
  float*  colS1   = (float*)(ws + (size_t)NROWS * 4);                  // K
  float*  colS2   = colS1 + KDIM;
  float*  colS3   = colS2 + KDIM;
  double* qsums   = (double*)(ws + (size_t)NROWS * 4 + 3 * KDIM * 4);  // 2 doubles
  float*  mean    = (float*)(ws + (size_t)NROWS * 4 + 3 * KDIM * 4 + 16);
  float*  inv_std = mean + KDIM;
  short8* c1tH    = (short8*)(ws + 276480);                            // 512 KB (16B aligned)

  hipMemsetAsync(colS1, 0, 3 * KDIM * 4 + 16, stream);

  prep_c1<<<128, 256, 0, stream>>>(C1, c1tH);
  quad_kernel<<<NROWS / BM, 1024, 0, stream>>>(X, c1tH, quad,
                                               colS1, colS2, colS3, qsums);
  finalize_kernel<<<2, 256, 0, stream>>>(colS1, colS2, colS3, qsums, C2, C3, mean, inv_std);
  normalize_kernel<<<(NROWS * (KDIM / 4)) / 256, 256, 0, stream>>>(
      X, quad, C2, C3, mean, inv_std, out);
}

// Round 18
// 120.679 us; speedup vs baseline: 1.1312x; 1.1312x over previous
//
#include <hip/hip_runtime.h>
#include <hip/hip_bf16.h>

#define NROWS 65536
#define KDIM  512
constexpr float BN_EPS = 1e-5f;

using short8 = __attribute__((ext_vector_type(8))) short;
using f32x4  = __attribute__((ext_vector_type(4))) float;

#define BM 128

// async global->LDS, 16B per lane (dest MUST be uniform base + lane*16 — m104)
__device__ __forceinline__ void gload_lds16(const void* g, void* l) {
  __builtin_amdgcn_global_load_lds(
      (const __attribute__((address_space(1))) void*)g,
      (__attribute__((address_space(3))) void*)l, 16, 0, 0);
}

__device__ __forceinline__ short bf16bits(float x) {
  __hip_bfloat16 h = __float2bfloat16(x);    // RNE, HW v_cvt_pk-fusible
  return *reinterpret_cast<short*>(&h);
}
__device__ __forceinline__ short8 cvt8(const float4& a, const float4& b) {
  short8 h;
  h[0] = bf16bits(a.x); h[1] = bf16bits(a.y); h[2] = bf16bits(a.z); h[3] = bf16bits(a.w);
  h[4] = bf16bits(b.x); h[5] = bf16bits(b.y); h[6] = bf16bits(b.z); h[7] = bf16bits(b.w);
  return h;
}

// ---------------- prep: C1 -> fragment-tiled bf16 (RNE) ----------------
// entry e = kg*512 + col holds C1[kg*8 + i][col], i=0..7 (one B-fragment).
__global__ __launch_bounds__(256)
void prep_c1(const float* __restrict__ C1, short8* __restrict__ c1tH) {
  const int e   = blockIdx.x * 256 + threadIdx.x;   // 0..32767
  const int col = e & 511;
  const int kg  = e >> 9;
  short8 hi;
  #pragma unroll
  for (int i = 0; i < 8; ++i)
    hi[i] = bf16bits(C1[(size_t)(kg * 8 + i) * KDIM + col]);   // coalesced
  c1tH[e] = hi;
}

// ---------------- quad: 64-row waves, 3-buffer counted-vmcnt pipeline ----------------
// quad[n] = x_n^T C1 x_n (1-pass bf16 MFMA), fused column stats.
// 8 waves = 2 row-groups (64 rows) x 4 col-groups (128 cols); BM=128.
// Taller wave tile: each B fragment feeds 2 row-groups (LDS B-reads halve
// vs the 32-row tile); acc = 128 AGPR; launch_bounds(512,2) caps unified
// regs at 256 (live ~220, no spill expected).
// Per phase kt: issue stage(kt+2) (B 32KB bf16 + A 16KB fp32, all DMA
// rounds dest = base + lane*16); compute kt from LDS (8 A ds_reads + cvt
// + 8 B ds_reads + 32 MFMA); s_waitcnt vmcnt(6) (completes stage(kt+1),
// leaves stage(kt+2) in flight) + s_barrier.
__global__ __launch_bounds__(512, 2)
void quad_kernel(const float* __restrict__ X, const short8* __restrict__ c1tH,
                 float* __restrict__ quad,
                 float* __restrict__ colS1, float* __restrict__ colS2,
                 float* __restrict__ colS3, double* __restrict__ qsumsA) {
  __shared__ short8 Bs[3][2048];      // 3 x 32 KB (bf16 fragment-tiled)
  __shared__ float  As[3][4096];      // 3 x 16 KB (fp32 [128][32], chunk-swizzled)
  __shared__ float qPart[4][BM];
  __shared__ float qLds[BM];

  const int tid  = threadIdx.x;
  const int lane = tid & 63;
  const int w    = tid >> 6;          // wave 0..7
  const int wr   = w >> 2;            // row-group (0..1): rows wr*64..+63
  const int wc   = w & 3;             // col-group (0..3): cols wc*128..+127
  const int g    = lane >> 4;         // k-group 0..3
  const int lr   = lane & 15;
  const int bid  = blockIdx.x;
  const int r0   = bid * BM;

  // A staging: two rounds, round s covers chunk-slot f = s*512 + tid
  // (row = f>>3, slot c = f&7; source chunk = c ^ (row&7) pre-swizzle).
  // Dest = As + f*16B -> uniform base + lane*16 per round. (64+row)&7 == row&7.
  const int arow = tid >> 3;
  const int ac   = tid & 7;
  const float* asrc0 = X + (size_t)(r0 + arow) * KDIM + ((ac ^ (arow & 7)) * 4);
  const float* asrc1 = asrc0 + (size_t)64 * KDIM;

#define STAGE(bufi, kt)                                                    \
  {                                                                        \
    gload_lds16(c1tH + (kt) * 2048 + tid,        &Bs[bufi][tid]);          \
    gload_lds16(c1tH + (kt) * 2048 + 512 + tid,  &Bs[bufi][512 + tid]);    \
    gload_lds16(c1tH + (kt) * 2048 + 1024 + tid, &Bs[bufi][1024 + tid]);   \
    gload_lds16(c1tH + (kt) * 2048 + 1536 + tid, &Bs[bufi][1536 + tid]);   \
    gload_lds16(asrc0 + (kt) * 32, &As[bufi][tid * 4]);                    \
    gload_lds16(asrc1 + (kt) * 32, &As[bufi][(512 + tid) * 4]);            \
  }

  f32x4 acc[4][8];
  #pragma unroll
  for (int rf = 0; rf < 4; ++rf)
    #pragma unroll
    for (int cf = 0; cf < 8; ++cf)
      acc[rf][cf] = (f32x4){0.f, 0.f, 0.f, 0.f};

  // ---- prologue: stage kt=0,1; wait only kt=0 (6 loads of kt=1 in flight) ----
  STAGE(0, 0);
  STAGE(1, 1);
  asm volatile("s_waitcnt vmcnt(6)" ::: "memory");
  __builtin_amdgcn_s_barrier();
  __builtin_amdgcn_sched_barrier(0);

  #pragma unroll
  for (int kt = 0; kt < 16; ++kt) {
    const int buf = kt % 3;
    if (kt < 14) STAGE((kt + 2) % 3, kt + 2);
    // ---- A fragments: 8 swizzled ds_read_b128 + HW cvt ----
    short8 Af[4];
    #pragma unroll
    for (int rf = 0; rf < 4; ++rf) {
      const int row = wr * 64 + rf * 16 + lr;
      const float4 x0 = *(const float4*)&As[buf][row * 32 + (((2 * g) ^ (row & 7)) * 4)];
      const float4 x1 = *(const float4*)&As[buf][row * 32 + (((2 * g + 1) ^ (row & 7)) * 4)];
      Af[rf] = cvt8(x0, x1);
    }
    // ---- B fragments + 32 MFMA ----
    const int fb = g * 512 + wc * 128 + lr;
    {
      const short8 b0 = Bs[buf][fb];
      const short8 b1 = Bs[buf][fb + 16];
      const short8 b2 = Bs[buf][fb + 32];
      const short8 b3 = Bs[buf][fb + 48];
      #pragma unroll
      for (int rf = 0; rf < 4; ++rf) {
        acc[rf][0] = __builtin_amdgcn_mfma_f32_16x16x32_bf16(Af[rf], b0, acc[rf][0], 0, 0, 0);
        acc[rf][1] = __builtin_amdgcn_mfma_f32_16x16x32_bf16(Af[rf], b1, acc[rf][1], 0, 0, 0);
        acc[rf][2] = __builtin_amdgcn_mfma_f32_16x16x32_bf16(Af[rf], b2, acc[rf][2], 0, 0, 0);
        acc[rf][3] = __builtin_amdgcn_mfma_f32_16x16x32_bf16(Af[rf], b3, acc[rf][3], 0, 0, 0);
      }
    }
    {
      const short8 b4 = Bs[buf][fb + 64];
      const short8 b5 = Bs[buf][fb + 80];
      const short8 b6 = Bs[buf][fb + 96];
      const short8 b7 = Bs[buf][fb + 112];
      #pragma unroll
      for (int rf = 0; rf < 4; ++rf) {
        acc[rf][4] = __builtin_amdgcn_mfma_f32_16x16x32_bf16(Af[rf], b4, acc[rf][4], 0, 0, 0);
        acc[rf][5] = __builtin_amdgcn_mfma_f32_16x16x32_bf16(Af[rf], b5, acc[rf][5], 0, 0, 0);
        acc[rf][6] = __builtin_amdgcn_mfma_f32_16x16x32_bf16(Af[rf], b6, acc[rf][6], 0, 0, 0);
        acc[rf][7] = __builtin_amdgcn_mfma_f32_16x16x32_bf16(Af[rf], b7, acc[rf][7], 0, 0, 0);
      }
    }
    // ---- counted pre-barrier wait: stage(kt+1) done, stage(kt+2) in flight ----
    if (kt < 14) {
      asm volatile("s_waitcnt vmcnt(6)" ::: "memory");
    } else if (kt == 14) {
      asm volatile("s_waitcnt vmcnt(0)" ::: "memory");
    }
    if (kt < 15) {
      __builtin_amdgcn_s_barrier();
      __builtin_amdgcn_sched_barrier(0);
    }
  }
#undef STAGE

  // ---- epilogue: row-dot against X for this wave's 128-col slice ----
  #pragma unroll
  for (int rf = 0; rf < 4; ++rf)
    #pragma unroll
    for (int p = 0; p < 4; ++p) {
      const int row = wr * 64 + rf * 16 + g * 4 + p;
      const float* xr = X + (size_t)(r0 + row) * KDIM + wc * 128;
      float s = 0.f;
      #pragma unroll
      for (int cf = 0; cf < 8; ++cf)
        s += acc[rf][cf][p] * xr[cf * 16 + lr];
      s += __shfl_xor(s, 1, 64);
      s += __shfl_xor(s, 2, 64);
      s += __shfl_xor(s, 4, 64);
      s += __shfl_xor(s, 8, 64);
      if (lr == 0) qPart[wc][row] = s;
    }
  __syncthreads();
  if (tid < BM) {
    const float q = qPart[0][tid] + qPart[1][tid] + qPart[2][tid] + qPart[3][tid];
    quad[r0 + tid] = q;
    qLds[tid] = q;
  }
  __syncthreads();
  // ---- fused column stats (4-copy colS arrays: 128 blocks/address) ----
  {
    const int cb = (bid & 3) * 512;
    float s1 = 0.f, s2 = 0.f, s3 = 0.f;
    for (int r = 0; r < BM; ++r) {
      const float q = qLds[r];
      const float x = X[(size_t)(r0 + r) * KDIM + tid];
      s1 += x; s2 += x * x; s3 += q * x;
    }
    atomicAdd(&colS1[cb + tid], s1);
    atomicAdd(&colS2[cb + tid], s2);
    atomicAdd(&colS3[cb + tid], s3);
  }
  if (tid < BM) {   // 32-slot spread qsums (16 blocks/address)
    double q = (double)qLds[tid];
    double q2 = q * q;
    #pragma unroll
    for (int m = 1; m < 64; m <<= 1) {
      q  += __shfl_xor(q,  m, 64);
      q2 += __shfl_xor(q2, m, 64);
    }
    if ((tid & 63) == 0) {
      atomicAdd(&qsumsA[(bid & 31) * 2],     q);
      atomicAdd(&qsumsA[(bid & 31) * 2 + 1], q2);
    }
  }
}

// ---------------- finalize per-feature mean / inv_std ----------------
__global__ void finalize_kernel(const float* __restrict__ colS1, const float* __restrict__ colS2,
                                const float* __restrict__ colS3, const double* __restrict__ qsumsA,
                                const float* __restrict__ C2, const float* __restrict__ C3,
                                float* __restrict__ mean, float* __restrict__ inv_std) {
  __shared__ double sQ[2];
  if (threadIdx.x == 0) {
    double a = 0.0, b = 0.0;
    for (int i = 0; i < 32; ++i) { a += qsumsA[2 * i]; b += qsumsA[2 * i + 1]; }
    sQ[0] = a; sQ[1] = b;
  }
  __syncthreads();
  const int k = blockIdx.x * blockDim.x + threadIdx.x;
  if (k >= KDIM) return;
  const double invN = 1.0 / (double)NROWS;
  const double meanQ = sQ[0] * invN;
  const double varQ  = sQ[1] * invN - meanQ * meanQ;
  const float meanX = (colS1[k] + colS1[k + 512] + colS1[k + 1024] + colS1[k + 1536]) * (float)invN;
  const float s2    = (colS2[k] + colS2[k + 512] + colS2[k + 1024] + colS2[k + 1536]) * (float)invN;
  const float s3    = (colS3[k] + colS3[k + 512] + colS3[k + 1024] + colS3[k + 1536]) * (float)invN;
  const float varX  = s2 - meanX * meanX;
  const float covQX = s3 - (float)meanQ * meanX;
  const float c2 = C2[k];
  const float c3 = C3[0];
  const float m = (float)meanQ + c2 * meanX + c3;
  const float v = (float)varQ + c2 * c2 * varX + 2.0f * c2 * covQX;
  mean[k] = m;
  inv_std[k] = 1.0f / sqrtf(v + BN_EPS);
}

// ---------------- normalize + write ----------------
__global__ __launch_bounds__(256)
void normalize_kernel(const float* __restrict__ X, const float* __restrict__ quad,
                      const float* __restrict__ C2, const float* __restrict__ C3,
                      const float* __restrict__ mean, const float* __restrict__ inv_std,
                      float* __restrict__ out) {
  const int idx = blockIdx.x * blockDim.x + threadIdx.x;  // float4 index
  const int n = idx >> 7;
  const int j4 = idx & 127;
  const float q = quad[n];
  const float c3 = C3[0];
  const float4 x  = *(const float4*)&X[(size_t)idx * 4];
  const float4 c2 = *(const float4*)&C2[j4 * 4];
  const float4 m  = *(const float4*)&mean[j4 * 4];
  const float4 iv = *(const float4*)&inv_std[j4 * 4];
  float4 o;
  o.x = (q + c2.x * x.x + c3 - m.x) * iv.x;
  o.y = (q + c2.y * x.y + c3 - m.y) * iv.y;
  o.z = (q + c2.z * x.z + c3 - m.z) * iv.z;
  o.w = (q + c2.w * x.w + c3 - m.w) * iv.w;
  *(float4*)&out[(size_t)idx * 4] = o;
}

extern "C" void kernel_launch(void* const* d_in, const int* in_sizes, int n_in,
                              void* d_out, int out_size, void* d_ws, size_t ws_size,
                              hipStream_t stream) {
  const float* X  = (const float*)d_in[0];
  const float* C1 = (const float*)d_in[1];
  const float* C2 = (const float*)d_in[2];
  const float* C3 = (const float*)d_in[3];
  float* out = (float*)d_out;

  char* ws = (char*)d_ws;
  float*  quad    = (float*)ws;                           // 262144 B
  float*  colS1   = (float*)(ws + 262144);                // 4 copies x 512 f
  float*  colS2   = (float*)(ws + 262144 + 8192);
  float*  colS3   = (float*)(ws + 262144 + 16384);
  double* qsumsA  = (double*)(ws + 262144 + 24576);       // 32 x {q, q2}
  float*  mean    = (float*)(ws + 262144 + 25088);
  float*  inv_std = (float*)(ws + 262144 + 27136);
  short8* c1tH    = (short8*)(ws + 294912);               // 512 KB, 16B-aligned

  // zero colS1..colS3 (24576 B) + qsumsA (512 B) — contiguous
  hipMemsetAsync(colS1, 0, 24576 + 512, stream);

  prep_c1<<<128, 256, 0, stream>>>(C1, c1tH);
  quad_kernel<<<NROWS / BM, 512, 0, stream>>>(X, c1tH, quad,
                                              colS1, colS2, colS3, qsumsA);
  finalize_kernel<<<2, 256, 0, stream>>>(colS1, colS2, colS3, qsumsA, C2, C3, mean, inv_std);
  normalize_kernel<<<(NROWS * (KDIM / 4)) / 256, 256, 0, stream>>>(
      X, quad, C2, C3, mean, inv_std, out);
}